// Round 1
// baseline (130.787 us; speedup 1.0000x reference)
//
#include <hip/hip_runtime.h>

#define BN 4
#define C 256
#define H 64
#define W 64
#define CM 64
#define G 16
#define GC 16
#define KS 7
#define K2 49
#define PADD 3
#define EPSV 1e-5f

// workspace layout (float offsets)
#define W1T_OFF 0                        // [256][64]  w1 transposed: w1T[c][o]
#define W2T_OFF (W1T_OFF + C*CM)         // [64][784]  w2 transposed: w2T[o][j]
#define S1_OFF  (W2T_OFF + CM*784)       // [64]
#define B1_OFF  (S1_OFF + CM)            // [64]
#define S2_OFF  (B1_OFF + CM)            // [256]
#define B2C_OFF (S2_OFF + C)             // [256]
#define T_OFF   (B2C_OFF + C)            // [4][64 tiles][64 o][64 pix] = 1048576
#define WS_FLOATS (T_OFF + BN*CM*H*W)

__global__ __launch_bounds__(256) void prep_kernel(
    const float* __restrict__ w1, const float* __restrict__ w2,
    const float* __restrict__ g1, const float* __restrict__ be1,
    const float* __restrict__ m1, const float* __restrict__ v1,
    const float* __restrict__ g2, const float* __restrict__ be2,
    const float* __restrict__ m2, const float* __restrict__ v2,
    float* __restrict__ ws) {
  int tid = blockIdx.x * 256 + threadIdx.x;
  int nthr = gridDim.x * 256;
  // transpose w1 [64][256] -> w1T [256][64]
  for (int i = tid; i < CM * C; i += nthr) {
    int o = i / C, c = i - o * C;
    ws[W1T_OFF + c * CM + o] = w1[i];
  }
  // transpose w2 [784][64] -> w2T [64][784]
  for (int i = tid; i < 784 * CM; i += nthr) {
    int j = i / CM, o = i - j * CM;
    ws[W2T_OFF + o * 784 + j] = w2[i];
  }
  if (tid < CM) {
    float inv = g1[tid] * rsqrtf(v1[tid] + EPSV);
    ws[S1_OFF + tid] = inv;
    ws[B1_OFF + tid] = be1[tid] - m1[tid] * inv;
  }
  if (tid < C) {
    float inv = g2[tid] * rsqrtf(v2[tid] + EPSV);
    ws[S2_OFF + tid] = inv;
    ws[B2C_OFF + tid] = be2[tid] - m2[tid] * inv;
  }
}

// t = relu(bn1(w1 @ x)), stored tile-contiguous:
// t[((b*64 + tile)*CM + o)*64 + pix], tile=(y>>3)*8+(x>>3), pix=(y&7)*8+(x&7)
__global__ __launch_bounds__(256) void t_kernel(
    const float* __restrict__ x, const float* __restrict__ ws,
    float* __restrict__ t) {
  __shared__ float part[4][CM][64];
  int p = threadIdx.x & 63;                                    // x coordinate
  int q = __builtin_amdgcn_readfirstlane(threadIdx.x >> 6);    // c-quarter (wave id)
  int y = blockIdx.x;
  int b = blockIdx.y;
  const float* __restrict__ w1T = ws + W1T_OFF;

  float acc[CM];
#pragma unroll
  for (int o = 0; o < CM; ++o) acc[o] = 0.f;

  const float* __restrict__ xrow = x + ((b * C + q * 64) * H + y) * W;
  for (int cc = 0; cc < 64; ++cc) {
    float xv = xrow[cc * H * W + p];
    const float* __restrict__ wr = w1T + (q * 64 + cc) * CM;   // scalar (uniform) loads
#pragma unroll
    for (int o = 0; o < CM; ++o) acc[o] = fmaf(wr[o], xv, acc[o]);
  }

#pragma unroll
  for (int o = 0; o < CM; ++o) part[q][o][p] = acc[o];
  __syncthreads();

  const float* __restrict__ s1 = ws + S1_OFF;
  const float* __restrict__ b1 = ws + B1_OFF;
  int tile = (y >> 3) * 8 + (p >> 3);
  int pix = (y & 7) * 8 + (p & 7);
#pragma unroll
  for (int i = 0; i < 16; ++i) {
    int o = q * 16 + i;
    float s = part[0][o][p] + part[1][o][p] + part[2][o][p] + part[3][o][p];
    float v = fmaf(s, s1[o], b1[o]);
    v = fmaxf(v, 0.f);
    t[((b * 64 + tile) * CM + o) * 64 + pix] = v;
  }
}

// per (b, group, 8x8 tile): wgt = w2T_g @ t + b2 (49 accs in VGPRs, one pixel
// per lane), then 7x7 involution from an LDS halo tile, bn2+relu, store.
__global__ __launch_bounds__(64) void inv_kernel(
    const float* __restrict__ x, const float* __restrict__ b2,
    const float* __restrict__ ws, const float* __restrict__ t,
    float* __restrict__ out) {
  __shared__ float t_lds[CM * 64];
  __shared__ float xh[14 * 14];
  int tid = threadIdx.x;
  int tile = blockIdx.x;
  int g = blockIdx.y;
  int b = blockIdx.z;
  int ty = (tile >> 3) * 8, tx = (tile & 7) * 8;
  int py = tid >> 3, px = tid & 7;

  // stage t tile (contiguous 16 KB), fully coalesced float4
  const float4* __restrict__ tt = (const float4*)(t + (size_t)(b * 64 + tile) * CM * 64);
  float4* t4 = (float4*)t_lds;
#pragma unroll
  for (int i = 0; i < 16; ++i) t4[i * 64 + tid] = tt[i * 64 + tid];
  __syncthreads();

  // wgt[k] = b2[g*49+k] + sum_o w2T[o][g*49+k] * t[o][pix]
  float wgt[K2];
  const float* __restrict__ b2g = b2 + g * K2;
#pragma unroll
  for (int k = 0; k < K2; ++k) wgt[k] = b2g[k];
  const float* __restrict__ w2Tg = ws + W2T_OFF + g * K2;
  for (int o = 0; o < CM; ++o) {
    float tv = t_lds[o * 64 + tid];
    const float* __restrict__ wr = w2Tg + o * 784;             // scalar (uniform) loads
#pragma unroll
    for (int k = 0; k < K2; ++k) wgt[k] = fmaf(wr[k], tv, wgt[k]);
  }

  const float* __restrict__ s2 = ws + S2_OFF;
  const float* __restrict__ b2c = ws + B2C_OFF;

  for (int cc = 0; cc < GC; ++cc) {
    int c = g * GC + cc;
    __syncthreads();  // protect xh from previous channel's readers
    const float* __restrict__ xc = x + (size_t)(b * C + c) * H * W;
#pragma unroll
    for (int ii = 0; ii < 4; ++ii) {
      int i = tid + ii * 64;
      if (i < 196) {
        int r = i / 14, cl = i - r * 14;
        int gy = ty - PADD + r, gx = tx - PADD + cl;
        float v = 0.f;
        if ((unsigned)gy < H && (unsigned)gx < W) v = xc[gy * W + gx];
        xh[i] = v;
      }
    }
    __syncthreads();

    float acc = 0.f;
    int base = py * 14 + px;
#pragma unroll
    for (int di = 0; di < KS; ++di)
#pragma unroll
      for (int dj = 0; dj < KS; ++dj)
        acc = fmaf(xh[base + di * 14 + dj], wgt[di * KS + dj], acc);

    float v = fmaf(acc, s2[c], b2c[c]);
    v = fmaxf(v, 0.f);
    out[((b * C + c) * H + ty + py) * W + tx + px] = v;
  }
}

extern "C" void kernel_launch(void* const* d_in, const int* in_sizes, int n_in,
                              void* d_out, int out_size, void* d_ws, size_t ws_size,
                              hipStream_t stream) {
  const float* x   = (const float*)d_in[0];
  const float* w1  = (const float*)d_in[1];
  const float* g1  = (const float*)d_in[2];
  const float* be1 = (const float*)d_in[3];
  const float* m1  = (const float*)d_in[4];
  const float* v1  = (const float*)d_in[5];
  const float* w2  = (const float*)d_in[6];
  const float* b2  = (const float*)d_in[7];
  const float* g2  = (const float*)d_in[8];
  const float* be2 = (const float*)d_in[9];
  const float* m2  = (const float*)d_in[10];
  const float* v2  = (const float*)d_in[11];
  float* outp = (float*)d_out;
  float* ws = (float*)d_ws;

  prep_kernel<<<dim3(64), dim3(256), 0, stream>>>(w1, w2, g1, be1, m1, v1,
                                                  g2, be2, m2, v2, ws);
  t_kernel<<<dim3(H, BN), dim3(256), 0, stream>>>(x, ws, ws + T_OFF);
  inv_kernel<<<dim3(64, G, BN), dim3(64), 0, stream>>>(x, b2, ws, ws + T_OFF, outp);
}